// Round 3
// baseline (165.041 us; speedup 1.0000x reference)
//
#include <hip/hip_runtime.h>
#include <stdint.h>

#define SEQ   4096
#define MARG  60000.0f
// denom = 4096*4095*1000
#define DENOM 16773120000.0
#define NBLK  1024

// ws layout:
//   cnt     : uint32         @ 0        (zeroed by memset node each call)
//   tglobal : float[1024]    @ 256      (atomic column sums; zeroed by memset)
//   spart   : float[1024]    @ 8192     (plain; every slot written every call)
//   dpart   : float[4][4096] @ 16384    (plain; a>=1 written; a==0 never read)

__device__ __forceinline__ float dot4(float4 a) {
  return a.x * a.x + a.y * a.y + a.z * a.z + a.w * a.w;
}
__device__ __forceinline__ float dist2(float4 a, float4 b) {
  float dx = a.x - b.x, dy = a.y - b.y, dz = a.z - b.z, dw = a.w - b.w;
  return dx * dx + dy * dy + dz * dz + dw * dw;
}
__device__ __forceinline__ float wred(float v) {
  #pragma unroll
  for (int o = 32; o; o >>= 1) v += __shfl_down(v, o, 64);
  return v;
}
__device__ __forceinline__ double wredd(double v) {
  #pragma unroll
  for (int o = 32; o; o >>= 1) v += __shfl_down(v, o, 64);
  return v;
}

// One fused kernel: streaming pass + last-block final reduction.
__global__ __launch_bounds__(256) void fused_kernel(
    const float* __restrict__ x, float* __restrict__ dpart,
    float* __restrict__ spart, float* __restrict__ tglobal,
    unsigned int* __restrict__ cnt, float* __restrict__ out) {
  const int b    = blockIdx.x;          // 0..1023
  const int n    = b >> 8;              // batch 0..3
  const int c    = b & 255;             // 16-timestep chunk
  const int tid  = threadIdx.x;
  const int w    = tid >> 6, lane = tid & 63;
  const int s0   = c * 16 + w * 4;      // wave's first timestep
  const float* rowp = x + (((size_t)(n * SEQ + s0)) << 8) + (lane << 2);

  const float4 v0 = *(const float4*)(rowp);
  const float4 v1 = *(const float4*)(rowp + 256);
  const float4 v2 = *(const float4*)(rowp + 512);
  const float4 v3 = *(const float4*)(rowp + 768);
  float4 vp;
  if (s0 > 0) vp = *(const float4*)(rowp - 256);  // previous timestep (boundary)
  else        vp = v0;                            // unused for s==0

  float4 tacc;
  tacc.x = v0.x + v1.x + v2.x + v3.x;
  tacc.y = v0.y + v1.y + v2.y + v3.y;
  tacc.z = v0.z + v1.z + v2.z + v3.z;
  tacc.w = v0.w + v1.w + v2.w + v3.w;
  const float s2 = dot4(v0) + dot4(v1) + dot4(v2) + dot4(v3);

  const float r0 = wred(dist2(v0, vp));
  const float r1 = wred(dist2(v1, v0));
  const float r2 = wred(dist2(v2, v1));
  const float r3 = wred(dist2(v3, v2));
  if (lane == 0) {
    float* dp = dpart + n * SEQ + s0;
    if (s0 > 0) dp[0] = r0;   // dpart[n][0] never read
    dp[1] = r1; dp[2] = r2; dp[3] = r3;
  }
  const float s2r = wred(s2);

  __shared__ float4 tl[4][64];
  __shared__ float  sl[4];
  tl[w][lane] = tacc;
  if (lane == 0) sl[w] = s2r;
  __syncthreads();
  if (w == 0) {
    const float4 a = tl[0][lane], bq = tl[1][lane], cq = tl[2][lane], dq = tl[3][lane];
    float* tg = tglobal + n * 256 + (lane << 2);
    unsafeAtomicAdd(tg + 0, a.x + bq.x + cq.x + dq.x);
    unsafeAtomicAdd(tg + 1, a.y + bq.y + cq.y + dq.y);
    unsafeAtomicAdd(tg + 2, a.z + bq.z + cq.z + dq.z);
    unsafeAtomicAdd(tg + 3, a.w + bq.w + cq.w + dq.w);
    if (lane == 0) spart[b] = sl[0] + sl[1] + sl[2] + sl[3];
  }

  // ---- arrival: last block performs the final reduction ----
  __threadfence();                       // release our stores/atomics
  __shared__ unsigned int lastflag;
  if (tid == 0) lastflag = atomicAdd(cnt, 1u);
  __syncthreads();
  if (lastflag != NBLK - 1) return;
  __threadfence();                       // acquire others' stores

  double t2 = 0.0, ss = 0.0, dsum = 0.0, hsum = 0.0;
  #pragma unroll
  for (int i = tid; i < 1024; i += 256) {
    const float t = tglobal[i];
    t2 += (double)t * (double)t;
    ss += (double)spart[i];
  }
  for (int a = tid; a < SEQ; a += 256) {
    if (a == 0) continue;
    const float D = dpart[a] + dpart[SEQ + a] + dpart[2 * SEQ + a] + dpart[3 * SEQ + a];
    dsum += (double)D;
    hsum += (double)fmaxf(0.f, MARG - D);
  }
  t2 = wredd(t2); ss = wredd(ss); dsum = wredd(dsum); hsum = wredd(hsum);
  __shared__ double rl[4][4];
  if (lane == 0) { rl[0][w] = t2; rl[1][w] = ss; rl[2][w] = dsum; rl[3][w] = hsum; }
  __syncthreads();
  if (tid == 0) {
    const double T2 = rl[0][0] + rl[0][1] + rl[0][2] + rl[0][3];
    const double S2 = rl[1][0] + rl[1][1] + rl[1][2] + rl[1][3];
    const double DS = rl[2][0] + rl[2][1] + rl[2][2] + rl[2][3];
    const double HS = rl[3][0] + rl[3][1] + rl[3][2] + rl[3][3];
    // num = Sum_{a>b} D - Sum_adj D + Sum_adj hinge
    //     = S*S2 - |t|^2 - dsum + hsum
    const double num = 4096.0 * S2 - T2 - DS + HS;
    out[0] = (float)(num / DENOM);
  }
}

extern "C" void kernel_launch(void* const* d_in, const int* in_sizes, int n_in,
                              void* d_out, int out_size, void* d_ws, size_t ws_size,
                              hipStream_t stream) {
  const float* x = (const float*)d_in[0];
  float* out = (float*)d_out;
  char* ws = (char*)d_ws;
  unsigned int* cnt  = (unsigned int*)ws;
  float* tglobal     = (float*)(ws + 256);
  float* spart       = (float*)(ws + 8192);
  float* dpart       = (float*)(ws + 16384);

  // zero counter + tglobal (init-agnostic to the 0xAA poison; capture-safe)
  hipMemsetAsync(ws, 0, 256 + 4096, stream);
  fused_kernel<<<NBLK, 256, 0, stream>>>(x, dpart, spart, tglobal, cnt, out);
}

// Round 11
// 70.423 us; speedup vs baseline: 2.3436x; 2.3436x over previous
//
#include <hip/hip_runtime.h>
#include <stdint.h>

#define SEQ   4096
#define MARG  60000.0f
// denom = 4096*4095*1000
#define DENOM 16773120000.0

// ws layout (plain stores only; every read location written every call):
//   tpart : float[256][256]  @ 0        (256 KB) per-block column-sum partials
//   spart : float[256]       @ 262144   (1 KB)   per-block sum-of-squares partials
//   dpart : float[4][4096]   @ 264192   (64 KB)  per-batch adjacent-pair dists

__device__ __forceinline__ float dot4(float4 a) {
  return a.x * a.x + a.y * a.y + a.z * a.z + a.w * a.w;
}
__device__ __forceinline__ float dist2(float4 a, float4 b) {
  float dx = a.x - b.x, dy = a.y - b.y, dz = a.z - b.z, dw = a.w - b.w;
  return dx * dx + dy * dy + dz * dz + dw * dw;
}
__device__ __forceinline__ float wred(float v) {
  #pragma unroll
  for (int o = 32; o; o >>= 1) v += __shfl_down(v, o, 64);
  return v;
}
__device__ __forceinline__ double wredd(double v) {
  #pragma unroll
  for (int o = 32; o; o >>= 1) v += __shfl_down(v, o, 64);
  return v;
}

// ---- K1: streaming pass. Block = (n, 64-timestep chunk); 8 waves x 8 rows.
// Lane holds float4 of features; one wave-step = one full 1KB row.
__global__ __launch_bounds__(512) void pass1_kernel(
    const float* __restrict__ x, float* __restrict__ dpart,
    float* __restrict__ tpart, float* __restrict__ spart) {
  const int b   = blockIdx.x;           // 0..255
  const int n   = b >> 6, c = b & 63;   // batch, chunk of 64 rows
  const int tid = threadIdx.x;
  const int w   = tid >> 6, lane = tid & 63;
  const int s0  = (c << 6) + (w << 3);  // wave's first timestep
  const float* base = x + (((size_t)((n << 12) + s0)) << 8) + (lane << 2);

  float4 v[8];
  #pragma unroll
  for (int r = 0; r < 8; ++r) v[r] = *(const float4*)(base + (r << 8));
  const float4 vp = (s0 > 0) ? *(const float4*)(base - 256) : v[0];

  float tx = 0.f, ty = 0.f, tz = 0.f, tw = 0.f, ss = 0.f;
  #pragma unroll
  for (int r = 0; r < 8; ++r) {
    tx += v[r].x; ty += v[r].y; tz += v[r].z; tw += v[r].w;
    ss += dot4(v[r]);
    const float d = wred(dist2(v[r], r ? v[r - 1] : vp));
    if (lane == 0) dpart[(n << 12) + s0 + r] = d;   // s==0 entry never read
  }
  ss = wred(ss);

  __shared__ float4 tl[8][64];
  __shared__ float  sl[8];
  tl[w][lane] = make_float4(tx, ty, tz, tw);
  if (lane == 0) sl[w] = ss;
  __syncthreads();
  if (w == 0) {
    float4 t = tl[0][lane];
    #pragma unroll
    for (int i = 1; i < 8; ++i) {
      t.x += tl[i][lane].x; t.y += tl[i][lane].y;
      t.z += tl[i][lane].z; t.w += tl[i][lane].w;
    }
    *(float4*)(tpart + (b << 8) + (lane << 2)) = t;
    if (lane == 0)
      spart[b] = sl[0] + sl[1] + sl[2] + sl[3] + sl[4] + sl[5] + sl[6] + sl[7];
  }
}

// ---- K2: fused treduce + finalize. One block, 1024 threads (16 waves).
__global__ __launch_bounds__(1024) void finalize_kernel(
    const float* __restrict__ tpart, const float* __restrict__ spart,
    const float* __restrict__ dpart, float* __restrict__ out) {
  const int tid = threadIdx.x;
  const int n = tid >> 8, f = tid & 255;   // thread owns t[n][f]
  float t = 0.f;
  #pragma unroll 8
  for (int c = 0; c < 64; ++c) t += tpart[(((n << 6) + c) << 8) + f];
  double t2 = (double)t * (double)t;
  double ss = (tid < 256) ? (double)spart[tid] : 0.0;
  double dsum = 0.0, hsum = 0.0;
  #pragma unroll
  for (int a = tid; a < SEQ; a += 1024) {
    if (a) {
      const float D = dpart[a] + dpart[SEQ + a] + dpart[2 * SEQ + a] + dpart[3 * SEQ + a];
      dsum += (double)D;
      hsum += (double)fmaxf(0.f, MARG - D);
    }
  }
  t2 = wredd(t2); ss = wredd(ss); dsum = wredd(dsum); hsum = wredd(hsum);
  __shared__ double rl[4][16];
  const int w = tid >> 6, lane = tid & 63;
  if (lane == 0) { rl[0][w] = t2; rl[1][w] = ss; rl[2][w] = dsum; rl[3][w] = hsum; }
  __syncthreads();
  if (tid == 0) {
    double T2 = 0, S2 = 0, DS = 0, HS = 0;
    #pragma unroll
    for (int i = 0; i < 16; ++i) {
      T2 += rl[0][i]; S2 += rl[1][i]; DS += rl[2][i]; HS += rl[3][i];
    }
    // num = Sum_{a>b} D - Sum_adj D + Sum_adj hinge = S*S2 - |t|^2 - DS + HS
    out[0] = (float)((4096.0 * S2 - T2 - DS + HS) / DENOM);
  }
}

extern "C" void kernel_launch(void* const* d_in, const int* in_sizes, int n_in,
                              void* d_out, int out_size, void* d_ws, size_t ws_size,
                              hipStream_t stream) {
  const float* x = (const float*)d_in[0];
  float* out = (float*)d_out;
  char* ws = (char*)d_ws;
  float* tpart = (float*)(ws);            // 256 KB
  float* spart = (float*)(ws + 262144);   // 1 KB
  float* dpart = (float*)(ws + 264192);   // 64 KB

  pass1_kernel<<<256, 512, 0, stream>>>(x, dpart, tpart, spart);
  finalize_kernel<<<1, 1024, 0, stream>>>(tpart, spart, dpart, out);
}